// Round 9
// baseline (257.941 us; speedup 1.0000x reference)
//
#include <hip/hip_runtime.h>
#include <hip/hip_bf16.h>

// ---------------------------------------------------------------------------
// GAT (2 layers) — round 25: packed-fp32 (v_pk_fma) GEMM inner loop.
// R24 post-mortem: D5 one-line records neutral (256.7->257.8) — als2 was
//   already L2-resident; only h-row gathers are real line services. Kept.
//   D3 floor re-confirmed (~50us, 148.8MB, 0 conflicts).
// R25: gemm_al_body accumulators -> v2f + __builtin_elementwise_fma so the
//   K-loop issues v_pk_fma_f32 (2 FMA/issue): 32 -> 16 VALU ops/k/thread.
//   Halves gemm1's 13.5us + D4's 3.3us machine-wide VALU. Applies to
//   D1/D2/D4 via the shared body; agg kernels untouched (line-bound, R10).
// Structure:
//   D1  scatter_gemm : 512-bucket slab sort + gemm1 [0,300).
//   D2  csr_gemm     : per-bucket CSR finalize + gemm1 [300,782).
//   D3  gat_agg<8,8> : edge-slot gather (structural floor ~50us).
//   D4  gemm_al (layer 2) -> 128B records (h2 + embedded al2).
//   D5  gat_agg<1,32,EMB> : one-line-per-edge gather -> out.
// Rejected by experiment: agg+gemm2 fusion (R12/R13/R21), STG=2048 (R17),
// GSPLIT=0 (R23), pipeline repack (R15), nt-loads (R6), packed-math in agg
// (R10 — line-service-bound; gemm is VALU-issue-bound, different regime).
// ---------------------------------------------------------------------------

#define SLAB  4096      // global per-bucket slab capacity (packed words)
#define STG   8192      // per-block staging slab (edges)
#define NBUCK 512
#define GSPLIT 300      // gemm1 blocks packed into D1

typedef float v2f __attribute__((ext_vector_type(2)));

__device__ __forceinline__ float lrelu02(float x) { return x > 0.f ? x : 0.2f * x; }

__device__ __forceinline__ unsigned short f2bf(float v) {
    __hip_bfloat16 b = __float2bfloat16(v);
    return __builtin_bit_cast(unsigned short, b);
}

__device__ __forceinline__ void accum8(uint4 hv, float ex, v2f* acc) {
    v2f ex2 = {ex, ex};
#pragma unroll
    for (int q = 0; q < 4; ++q) {
        unsigned u = (&hv.x)[q];
        v2f h2 = {__uint_as_float(u << 16), __uint_as_float(u & 0xffff0000u)};
        acc[q] = __builtin_elementwise_fma(h2, ex2, acc[q]);
    }
}

__device__ __forceinline__ v2f shfl_xor_v2(v2f v, int mask) {
    v2f r;
    r.x = __shfl_xor(v.x, mask, 64);
    r.y = __shfl_xor(v.y, mask, 64);
    return r;
}

// ----------------------- scatter body (512-bucket slab sort) ----------------
__device__ __forceinline__ void scatter_body(char* smem, int vbid,
                                             const int* __restrict__ ei,
                                             int e_real, int e_total, unsigned M,
                                             int* __restrict__ bcur_pad,
                                             unsigned* __restrict__ pairs) {
    int* cnt   = (int*)smem;                     // 512 (reused as lo[] later)
    int* loff  = cnt + 512;                      // 512
    int* lcur  = loff + 512;                     // 512
    int* gbase = lcur + 512;                     // 512
    int* sw    = gbase + 512;                    // STG packed words

    const int t = threadIdx.x;
    const int base = vbid * STG;
    cnt[t] = 0; cnt[t + 256] = 0;
    __syncthreads();

    int rs[STG / 256], rd[STG / 256], rb[STG / 256];
#pragma unroll
    for (int k = 0; k < STG / 256; ++k) {
        int i = base + k * 256 + t;
        bool val = i < e_total;
        int s = 0, d = 0;
        if (val) {
            if (i < e_real) { s = ei[i]; d = ei[e_real + i]; }
            else            { s = d = i - e_real; }
        }
        int b = val ? (int)__umulhi((unsigned)d, M) : -1;
        rs[k] = s; rd[k] = d; rb[k] = b;
        if (val) atomicAdd(&cnt[b], 1);
    }
    __syncthreads();

    loff[t] = cnt[t]; loff[t + 256] = cnt[t + 256];
    __syncthreads();
    for (int off = 1; off < 512; off <<= 1) {
        int v0 = (t >= off) ? loff[t - off] : 0;
        int v1 = (t + 256 >= off) ? loff[t + 256 - off] : 0;
        __syncthreads();
        loff[t] += v0; loff[t + 256] += v1;
        __syncthreads();
    }
    int e0 = loff[t] - cnt[t];
    int e1 = loff[t + 256] - cnt[t + 256];
    loff[t] = e0;           loff[t + 256] = e1;
    lcur[t] = e0;           lcur[t + 256] = e1;
    gbase[t]       = t * SLAB         + atomicAdd(&bcur_pad[t * 16], cnt[t]);
    gbase[t + 256] = (t + 256) * SLAB + atomicAdd(&bcur_pad[(t + 256) * 16],
                                                  cnt[t + 256]);
    // cnt[] is dead now — repurpose as lo[bucket] for the packed row index.
    {
        const unsigned long long Mll = M;
        cnt[t]       = (int)((((unsigned long long)t << 32) + Mll - 1) / Mll);
        cnt[t + 256] = (int)((((unsigned long long)(t + 256) << 32) + Mll - 1) / Mll);
    }
    __syncthreads();

#pragma unroll
    for (int k = 0; k < STG / 256; ++k) {
        if (rb[k] >= 0) {
            int lp = atomicAdd(&lcur[rb[k]], 1);
            sw[lp] = rs[k] | ((rd[k] - cnt[rb[k]]) << 17);
        }
    }
    __syncthreads();

    // emit per bucket: thread t owns buckets t and t+256; streams each run.
#pragma unroll
    for (int q = 0; q < 2; ++q) {
        int b  = t + q * 256;
        int s0 = loff[b];
        int cb = lcur[b] - s0;
        int g  = gbase[b];
        for (int j = 0; j < cb; ++j)
            pairs[g + j] = (unsigned)sw[s0 + j];
    }
}

// ------------------------- GEMM + attention logits body ---------------------
// RSTR  : h row stride (ushorts).  EMBAL : embed fp32 al_s/al_d at row
// slots 32/34 instead of writing the al arrays (layer-2 record mode).
// Accumulators are v2f so the K-loop issues v_pk_fma_f32 (2 FMA/op).
template<int K, int OUTC, int H, int C, int NPT, int KCHUNK,
         int RSTR = OUTC, bool EMBAL = false>
__device__ __forceinline__ void gemm_al_body(char* smem, int vbid,
                                             const float* __restrict__ x,
                                             const float* __restrict__ W,
                                             const float* __restrict__ a_src,
                                             const float* __restrict__ a_dst,
                                             unsigned short* __restrict__ h,
                                             float* __restrict__ al_s,
                                             float* __restrict__ al_d,
                                             int n) {
    constexpr int COLG = OUTC / 4;
    constexpr int NG   = 256 / COLG;
    static_assert(NG * 8 == NPT, "tile mismatch");
    constexpr int LDX  = KCHUNK + 1;
    float* Xs = (float*)smem;                 // NPT*LDX
    float* Ws = Xs + NPT * LDX;               // KCHUNK*OUTC

    const int t    = threadIdx.x;
    const int mg   = t / COLG;
    const int cg   = t % COLG;
    const int base = vbid * NPT;

    v2f acc[8][2];
#pragma unroll
    for (int i = 0; i < 8; ++i) {
        acc[i][0] = (v2f){0.f, 0.f};
        acc[i][1] = (v2f){0.f, 0.f};
    }

    for (int kc = 0; kc < K; kc += KCHUNK) {
        __syncthreads();
        constexpr int F4R = KCHUNK / 4;
        constexpr int TOTF4 = NPT * F4R;
#pragma unroll
        for (int r = 0; r < TOTF4 / 256; ++r) {
            int f4   = r * 256 + t;
            int node = f4 / F4R;
            int kq   = f4 % F4R;
            int gn   = base + node; if (gn > n - 1) gn = n - 1;
            const float4 v = *(const float4*)&x[(size_t)gn * K + kc + kq * 4];
            float* d = &Xs[node * LDX + kq * 4];
            d[0] = v.x; d[1] = v.y; d[2] = v.z; d[3] = v.w;
        }
        constexpr int WF4 = KCHUNK * OUTC / 4;
        for (int idx = t; idx < WF4; idx += 256)
            *(float4*)&Ws[idx * 4] = *(const float4*)&W[(size_t)kc * OUTC + idx * 4];
        __syncthreads();

#pragma unroll 4
        for (int k = 0; k < KCHUNK; ++k) {
            float4 b = *(const float4*)&Ws[k * OUTC + cg * 4];
            v2f b01 = {b.x, b.y};
            v2f b23 = {b.z, b.w};
#pragma unroll
            for (int i = 0; i < 8; ++i) {
                float av = Xs[(mg * 8 + i) * LDX + k];
                v2f a2 = {av, av};
                acc[i][0] = __builtin_elementwise_fma(a2, b01, acc[i][0]);
                acc[i][1] = __builtin_elementwise_fma(a2, b23, acc[i][1]);
            }
        }
    }

    const float4 as4 = *(const float4*)&a_src[cg * 4];
    const float4 ad4 = *(const float4*)&a_dst[cg * 4];
    constexpr int GPH = C / 4;
    const int head = cg / GPH;
#pragma unroll
    for (int i = 0; i < 8; ++i) {
        int gn = base + mg * 8 + i;
        bool ok = gn < n;
        float a0 = acc[i][0].x, a1 = acc[i][0].y;
        float a2 = acc[i][1].x, a3 = acc[i][1].y;
        if (ok) {
            ushort4 hv;
            hv.x = f2bf(a0); hv.y = f2bf(a1);
            hv.z = f2bf(a2); hv.w = f2bf(a3);
            *(ushort4*)&h[(size_t)gn * RSTR + cg * 4] = hv;
        }
        float ps = a0 * as4.x + a1 * as4.y + a2 * as4.z + a3 * as4.w;
        float pd = a0 * ad4.x + a1 * ad4.y + a2 * ad4.z + a3 * ad4.w;
#pragma unroll
        for (int s = 1; s < GPH; s <<= 1) {
            ps += __shfl_xor(ps, s, 64);
            pd += __shfl_xor(pd, s, 64);
        }
        if (ok && (cg % GPH) == 0) {
            if constexpr (EMBAL) {
                *(float*)&h[(size_t)gn * RSTR + 32] = ps;
                *(float*)&h[(size_t)gn * RSTR + 34] = pd;
            } else {
                al_s[(size_t)gn * H + head] = ps;
                al_d[(size_t)gn * H + head] = pd;
            }
        }
    }
}

// --------------------- CSR finalize body (smem-parameterized) ---------------
__device__ __forceinline__ void csr_body(char* smem, int b,
                                         const unsigned* __restrict__ pairs,
                                         const int* __restrict__ bcur_pad,
                                         unsigned M, int n,
                                         int* __restrict__ offsets,
                                         int* __restrict__ srcs) {
    int* bs  = (int*)smem;          // 512
    int* deg = bs + 512;            // 256
    int* sc  = deg + 256;           // 256
    int* cur = sc + 256;            // 256
    int* ebeg_p = cur + 256;        // 1

    const int t = threadIdx.x;
    const unsigned long long Mll = M;
    int lo = (int)((((unsigned long long)b << 32) + Mll - 1) / Mll);
    int hi = (int)((((unsigned long long)(b + 1) << 32) + Mll - 1) / Mll);
    if (lo > n) lo = n;
    if (hi > n) hi = n;
    const int R    = hi - lo;                 // <= ~196 < 256
    const int cntb = bcur_pad[b * 16];
    const unsigned* sp = pairs + (size_t)b * SLAB;

    bs[t] = bcur_pad[t * 16];
    bs[t + 256] = bcur_pad[(t + 256) * 16];
    __syncthreads();
    for (int off = 1; off < NBUCK; off <<= 1) {
        int v0 = (t >= off) ? bs[t - off] : 0;
        int v1 = (t + 256 >= off) ? bs[t + 256 - off] : 0;
        __syncthreads();
        bs[t] += v0; bs[t + 256] += v1;
        __syncthreads();
    }
    if (t == 0) *ebeg_p = (b == 0) ? 0 : bs[b - 1];
    if (b == NBUCK - 1 && t == 0) offsets[n] = bs[NBUCK - 1];
    __syncthreads();
    const int ebeg = *ebeg_p;

    deg[t] = 0;
    __syncthreads();
    for (int j = t; j < cntb; j += 256)
        atomicAdd(&deg[sp[j] >> 17], 1);
    __syncthreads();

    sc[t] = deg[t];
    __syncthreads();
    for (int off = 1; off < 256; off <<= 1) {
        int v = (t >= off) ? sc[t - off] : 0;
        __syncthreads();
        sc[t] += v;
        __syncthreads();
    }
    int e0 = sc[t] - deg[t];
    cur[t] = e0;
    if (t < R) offsets[lo + t] = ebeg + e0;
    __syncthreads();

    for (int j = t; j < cntb; j += 256) {
        unsigned w = sp[j];
        int pos = atomicAdd(&cur[w >> 17], 1);          // LDS atomic
        srcs[ebeg + pos] = (int)(w & 0x1FFFFu);
    }
}

// ------------- D1: scatter blocks + gemm1 blocks [0, GSPLIT) ---------------
__global__ __launch_bounds__(256)
void scatter_gemm_kernel(const int* __restrict__ ei, int e_real, int e_total,
                         unsigned M, int* __restrict__ bcur_pad,
                         unsigned* __restrict__ pairs, int ns,
                         const float* __restrict__ x,
                         const float* __restrict__ W1,
                         const float* __restrict__ as1,
                         const float* __restrict__ ad1,
                         unsigned short* __restrict__ h,
                         float* __restrict__ al_s,
                         float* __restrict__ al_d, int n) {
    __shared__ __align__(16) char smem[40960];  // max(gemm 25088, scatter 40960)
    if ((int)blockIdx.x < ns)
        scatter_body(smem, blockIdx.x, ei, e_real, e_total, M, bcur_pad, pairs);
    else
        gemm_al_body<128, 64, 8, 8, 128, 32>(smem, blockIdx.x - ns,
                                             x, W1, as1, ad1, h, al_s, al_d, n);
}

// ------------- D2: csr blocks (512) + gemm1 blocks [GSPLIT, 782) -----------
__global__ __launch_bounds__(256)
void csr_gemm_kernel(const unsigned* __restrict__ pairs,
                     const int* __restrict__ bcur_pad,
                     unsigned M,
                     int* __restrict__ offsets,
                     int* __restrict__ srcs,
                     const float* __restrict__ x,
                     const float* __restrict__ W1,
                     const float* __restrict__ as1,
                     const float* __restrict__ ad1,
                     unsigned short* __restrict__ h,
                     float* __restrict__ al_s,
                     float* __restrict__ al_d, int n) {
    __shared__ __align__(16) char smem[25088];  // max(gemm 25088, csr 5124)
    if ((int)blockIdx.x < NBUCK)
        csr_body(smem, blockIdx.x, pairs, bcur_pad, M, n, offsets, srcs);
    else
        gemm_al_body<128, 64, 8, 8, 128, 32>(smem,
                                             GSPLIT + ((int)blockIdx.x - NBUCK),
                                             x, W1, as1, ad1, h, al_s, al_d, n);
}

// D4: standalone layer-2 GEMM -> 128B records (h2 bf16[32] + fp32 al2 @32/34)
template<int K, int OUTC, int H, int C, int NPT, int KCHUNK, int RSTR, bool EMBAL>
__global__ __launch_bounds__(256)
void gemm_al_kernel(const float* __restrict__ x, const float* __restrict__ W,
                    const float* __restrict__ a_src, const float* __restrict__ a_dst,
                    unsigned short* __restrict__ h, float* __restrict__ al_s,
                    float* __restrict__ al_d, int n) {
    __shared__ __align__(16) char smem[(NPT * (KCHUNK + 1) + KCHUNK * OUTC) * 4];
    gemm_al_body<K, OUTC, H, C, NPT, KCHUNK, RSTR, EMBAL>(
        smem, blockIdx.x, x, W, a_src, a_dst, h, al_s, al_d, n);
}

// ------------------------- fused gather aggregation -------------------------
// wave = 1 dst node; lane = (edge_slot es, channel_group cg of 8 bf16).
// RSTR: hfeat row stride (ushorts). EMB: al_s/al_d embedded in the row as
// fp32 at slots 32/34 (one random line per edge).
template<int H, int C, int RSTR, bool EMB>
__global__ __launch_bounds__(256)
void gat_agg_kernel(const int* __restrict__ offsets,
                    const int* __restrict__ srcs,
                    const float* __restrict__ al_s,
                    const float* __restrict__ al_d,
                    const unsigned short* __restrict__ hfeat, // bf16 rows
                    const float* __restrict__ bias,
                    float* __restrict__ out, int n) {
    constexpr int OUTC = H * C;
    constexpr int CG   = OUTC / 8;           // channel groups (8 or 4)
    constexpr int ES   = 64 / CG;            // edge slots (8 or 16)
    const int wid  = (int)((blockIdx.x * blockDim.x + threadIdx.x) >> 6);
    const int lane = threadIdx.x & 63;
    const int cg   = lane % CG;
    const int es   = lane / CG;
    if (wid >= n) return;
    const int head = (cg * 8) / C;

    float aldv;
    if constexpr (EMB) aldv = *(const float*)&hfeat[(size_t)wid * RSTR + 34];
    else               aldv = al_d[(size_t)wid * H + head];
    const int beg = offsets[wid];
    const int end = offsets[wid + 1];
    const int deg = end - beg;

    v2f acc[4];
#pragma unroll
    for (int q = 0; q < 4; ++q) acc[q] = (v2f){0.f, 0.f};
    float dsum = 0.f;

#define LOADLS(sv) (EMB ? *(const float*)&hfeat[(size_t)(sv) * RSTR + 32] \
                        : al_s[(size_t)(sv) * H + head])

    if (deg <= ES) {
        int j = beg + es;
        bool v = j < end;
        int s = __builtin_nontemporal_load(&srcs[v ? j : beg]);
        const uint4 hv = *(const uint4*)&hfeat[(size_t)s * RSTR + cg * 8];
        float ls = LOADLS(s);
        float ex = v ? __expf(lrelu02(ls + aldv)) : 0.f;
        accum8(hv, ex, acc);
        dsum += ex;
    } else if (deg <= 2 * ES) {
        int sA = __builtin_nontemporal_load(&srcs[beg + es]);
        int jB = beg + ES + es;
        bool vB = jB < end;
        int sB = __builtin_nontemporal_load(&srcs[vB ? jB : beg]);
        const uint4 hvA = *(const uint4*)&hfeat[(size_t)sA * RSTR + cg * 8];
        const uint4 hvB = *(const uint4*)&hfeat[(size_t)sB * RSTR + cg * 8];
        float lsA = LOADLS(sA);
        float lsB = LOADLS(sB);
        float exA = __expf(lrelu02(lsA + aldv));
        float exB = vB ? __expf(lrelu02(lsB + aldv)) : 0.f;
        accum8(hvA, exA, acc);
        accum8(hvB, exB, acc);
        dsum += exA + exB;
    } else if (deg <= 4 * ES) {
        int sA = __builtin_nontemporal_load(&srcs[beg + es]);
        int sB = __builtin_nontemporal_load(&srcs[beg + ES + es]);
        int jC = beg + 2 * ES + es;
        int jD = beg + 3 * ES + es;
        bool vC = jC < end;
        bool vD = jD < end;
        int sC = __builtin_nontemporal_load(&srcs[vC ? jC : beg]);
        int sD = __builtin_nontemporal_load(&srcs[vD ? jD : beg]);
        const uint4 hvA = *(const uint4*)&hfeat[(size_t)sA * RSTR + cg * 8];
        const uint4 hvB = *(const uint4*)&hfeat[(size_t)sB * RSTR + cg * 8];
        const uint4 hvC = *(const uint4*)&hfeat[(size_t)sC * RSTR + cg * 8];
        const uint4 hvD = *(const uint4*)&hfeat[(size_t)sD * RSTR + cg * 8];
        float lsA = LOADLS(sA);
        float lsB = LOADLS(sB);
        float lsC = LOADLS(sC);
        float lsD = LOADLS(sD);
        float exA = __expf(lrelu02(lsA + aldv));
        float exB = __expf(lrelu02(lsB + aldv));
        float exC = vC ? __expf(lrelu02(lsC + aldv)) : 0.f;
        float exD = vD ? __expf(lrelu02(lsD + aldv)) : 0.f;
        accum8(hvA, exA, acc);
        accum8(hvB, exB, acc);
        accum8(hvC, exC, acc);
        accum8(hvD, exD, acc);
        dsum += (exA + exB) + (exC + exD);
    } else {
        for (int j0 = beg; j0 < end; j0 += 2 * ES) {
            int jA = j0 + es;
            int jB = j0 + ES + es;
            bool vA = jA < end;
            bool vB = jB < end;
            int sA = __builtin_nontemporal_load(&srcs[vA ? jA : beg]);
            int sB = __builtin_nontemporal_load(&srcs[vB ? jB : beg]);
            const uint4 hvA = *(const uint4*)&hfeat[(size_t)sA * RSTR + cg * 8];
            const uint4 hvB = *(const uint4*)&hfeat[(size_t)sB * RSTR + cg * 8];
            float lsA = LOADLS(sA);
            float lsB = LOADLS(sB);
            float exA = vA ? __expf(lrelu02(lsA + aldv)) : 0.f;
            float exB = vB ? __expf(lrelu02(lsB + aldv)) : 0.f;
            accum8(hvA, exA, acc);
            accum8(hvB, exB, acc);
            dsum += exA + exB;
        }
    }
#undef LOADLS

#pragma unroll
    for (int sh = CG; sh < 64; sh <<= 1) {
        dsum += __shfl_xor(dsum, sh, 64);
#pragma unroll
        for (int q = 0; q < 4; ++q) acc[q] += shfl_xor_v2(acc[q], sh);
    }

    if (es == 0) {
        float inv = 1.f / dsum;
        const float4 b0 = *(const float4*)&bias[cg * 8];
        const float4 b1v = *(const float4*)&bias[cg * 8 + 4];
        float4 o0, o1;
        o0.x = acc[0].x * inv + b0.x;
        o0.y = acc[0].y * inv + b0.y;
        o0.z = acc[1].x * inv + b0.z;
        o0.w = acc[1].y * inv + b0.w;
        o1.x = acc[2].x * inv + b1v.x;
        o1.y = acc[2].y * inv + b1v.y;
        o1.z = acc[3].x * inv + b1v.z;
        o1.w = acc[3].y * inv + b1v.w;
        *(float4*)&out[(size_t)wid * OUTC + cg * 8]     = o0;
        *(float4*)&out[(size_t)wid * OUTC + cg * 8 + 4] = o1;
    }
}

// ---------------------------------------------------------------------------

extern "C" void kernel_launch(void* const* d_in, const int* in_sizes, int n_in,
                              void* d_out, int out_size, void* d_ws, size_t ws_size,
                              hipStream_t stream) {
    const float* x   = (const float*)d_in[0];
    const int*   ei  = (const int*)  d_in[1];
    const float* W1  = (const float*)d_in[2];
    const float* as1 = (const float*)d_in[3];
    const float* ad1 = (const float*)d_in[4];
    const float* b1  = (const float*)d_in[5];
    const float* W2  = (const float*)d_in[6];
    const float* as2 = (const float*)d_in[7];
    const float* ad2 = (const float*)d_in[8];
    const float* b2  = (const float*)d_in[9];
    float* out = (float*)d_out;

    const int n       = in_sizes[0] / 128;   // 100000
    const int e_real  = in_sizes[1] / 2;     // 1600000
    const int e_total = e_real + n;
    const unsigned M512 = (unsigned)(((unsigned long long)NBUCK << 32) / (unsigned)n);

    // ------------- workspace layout -------------
    unsigned short* h1u = (unsigned short*)d_ws;       // n*64 bf16 (layer-1 h;
                                                       //  reused as 128B recs)
    float* fws  = (float*)d_ws;
    float* als1 = fws  + (size_t)n * 32;               // n*8
    float* ald1 = als1 + (size_t)n * 8;                // n*8
    float* agg1 = ald1 + (size_t)n * 8;                // n*64 fp32 (layer1 out)
    unsigned* pairs = (unsigned*)agg1;                 // ALIAS: NBUCK*SLAB u32
    int* offsets  = (int*)(agg1 + (size_t)n * 64);     // n+1
    int* srcs     = offsets + (n + 1);                 // e_total
    int* bcur_pad = srcs + e_total;                    // NBUCK*16

    const int ns = (e_total + STG - 1) / STG;          // scatter blocks (208)
    const int g1 = (n + 127) / 128;                    // gemm1 blocks (782)

    // ------------- D1: scatter + gemm1[0,GSPLIT) -------------
    hipMemsetAsync(bcur_pad, 0, NBUCK * 16 * sizeof(int), stream);
    scatter_gemm_kernel<<<ns + GSPLIT, 256, 0, stream>>>(
        ei, e_real, e_total, M512, bcur_pad, pairs, ns,
        x, W1, as1, ad1, h1u, als1, ald1, n);

    // ------------- D2: csr finalize + gemm1[GSPLIT,g1) -------------
    csr_gemm_kernel<<<NBUCK + (g1 - GSPLIT), 256, 0, stream>>>(
        pairs, bcur_pad, M512, offsets, srcs,
        x, W1, as1, ad1, h1u, als1, ald1, n);

    // ------------- D3: layer 1 aggregation -------------
    gat_agg_kernel<8, 8, 64, false><<<(n + 3) / 4, 256, 0, stream>>>(
        offsets, srcs, als1, ald1, h1u, b1, agg1, n);

    // ------------- D4: layer 2 GEMM -> 128B records in h1u region --------
    gemm_al_kernel<64, 32, 1, 32, 256, 32, 64, true>
        <<<(n + 255) / 256, 256, 0, stream>>>(
        agg1, W2, as2, ad2, h1u, nullptr, nullptr, n);

    // ------------- D5: layer 2 aggregation (one line per edge) -----------
    gat_agg_kernel<1, 32, 64, true><<<(n + 3) / 4, 256, 0, stream>>>(
        offsets, srcs, nullptr, nullptr, h1u, b2, out, n);
}

// Round 10
// 255.744 us; speedup vs baseline: 1.0086x; 1.0086x over previous
//
#include <hip/hip_runtime.h>
#include <hip/hip_bf16.h>

// ---------------------------------------------------------------------------
// GAT (2 layers) — round 26: bf16 agg1 round-trip (D3 out / D4 in).
// R25 post-mortem: packed-fp32 gemm neutral — gemm VALU fully hidden under
//   scatter/csr latency; D1/D2 bound by serial paths. Kept (harmless).
//   Top-5 = 5 iterations of D3 -> all other dispatches < 49.6us.
// R26: agg1 (25.6MB fp32) exists only as D3->D4 round-trip. Write bf16:
//   D3 WRITE 25->12.5MB, D4 read 25.6->12.8MB. Precision: adds 2^-9 rel
//   rounding on gemm2 inputs (h1/h2 already bf16-rounded); absmax expected
//   0.0078 -> ~0.012-0.016.
// Structure:
//   D1  scatter_gemm : 512-bucket slab sort + gemm1 [0,300).
//   D2  csr_gemm     : per-bucket CSR finalize + gemm1 [300,782).
//   D3  gat_agg<8,8,OBF> : edge-slot gather -> bf16 agg1.
//   D4  gemm_al<INBF> (layer 2) -> 128B records (h2 + embedded al2).
//   D5  gat_agg<1,32,EMB> : one-line-per-edge gather -> out.
// Rejected by experiment: agg+gemm2 fusion (R12/R13/R21), STG=2048 (R17),
// GSPLIT=0 (R23), pipeline repack (R15), nt-loads (R6), packed-math in agg
// (R10), D5 record-embedding gain (R24 neutral), packed gemm fp32 (R25
// neutral — latency-hidden).
// ---------------------------------------------------------------------------

#define SLAB  4096      // global per-bucket slab capacity (packed words)
#define STG   8192      // per-block staging slab (edges)
#define NBUCK 512
#define GSPLIT 300      // gemm1 blocks packed into D1

typedef float v2f __attribute__((ext_vector_type(2)));

__device__ __forceinline__ float lrelu02(float x) { return x > 0.f ? x : 0.2f * x; }

__device__ __forceinline__ unsigned short f2bf(float v) {
    __hip_bfloat16 b = __float2bfloat16(v);
    return __builtin_bit_cast(unsigned short, b);
}

__device__ __forceinline__ float bf2f(unsigned short u) {
    return __uint_as_float(((unsigned)u) << 16);
}

__device__ __forceinline__ void accum8(uint4 hv, float ex, v2f* acc) {
    v2f ex2 = {ex, ex};
#pragma unroll
    for (int q = 0; q < 4; ++q) {
        unsigned u = (&hv.x)[q];
        v2f h2 = {__uint_as_float(u << 16), __uint_as_float(u & 0xffff0000u)};
        acc[q] = __builtin_elementwise_fma(h2, ex2, acc[q]);
    }
}

__device__ __forceinline__ v2f shfl_xor_v2(v2f v, int mask) {
    v2f r;
    r.x = __shfl_xor(v.x, mask, 64);
    r.y = __shfl_xor(v.y, mask, 64);
    return r;
}

// ----------------------- scatter body (512-bucket slab sort) ----------------
__device__ __forceinline__ void scatter_body(char* smem, int vbid,
                                             const int* __restrict__ ei,
                                             int e_real, int e_total, unsigned M,
                                             int* __restrict__ bcur_pad,
                                             unsigned* __restrict__ pairs) {
    int* cnt   = (int*)smem;                     // 512 (reused as lo[] later)
    int* loff  = cnt + 512;                      // 512
    int* lcur  = loff + 512;                     // 512
    int* gbase = lcur + 512;                     // 512
    int* sw    = gbase + 512;                    // STG packed words

    const int t = threadIdx.x;
    const int base = vbid * STG;
    cnt[t] = 0; cnt[t + 256] = 0;
    __syncthreads();

    int rs[STG / 256], rd[STG / 256], rb[STG / 256];
#pragma unroll
    for (int k = 0; k < STG / 256; ++k) {
        int i = base + k * 256 + t;
        bool val = i < e_total;
        int s = 0, d = 0;
        if (val) {
            if (i < e_real) { s = ei[i]; d = ei[e_real + i]; }
            else            { s = d = i - e_real; }
        }
        int b = val ? (int)__umulhi((unsigned)d, M) : -1;
        rs[k] = s; rd[k] = d; rb[k] = b;
        if (val) atomicAdd(&cnt[b], 1);
    }
    __syncthreads();

    loff[t] = cnt[t]; loff[t + 256] = cnt[t + 256];
    __syncthreads();
    for (int off = 1; off < 512; off <<= 1) {
        int v0 = (t >= off) ? loff[t - off] : 0;
        int v1 = (t + 256 >= off) ? loff[t + 256 - off] : 0;
        __syncthreads();
        loff[t] += v0; loff[t + 256] += v1;
        __syncthreads();
    }
    int e0 = loff[t] - cnt[t];
    int e1 = loff[t + 256] - cnt[t + 256];
    loff[t] = e0;           loff[t + 256] = e1;
    lcur[t] = e0;           lcur[t + 256] = e1;
    gbase[t]       = t * SLAB         + atomicAdd(&bcur_pad[t * 16], cnt[t]);
    gbase[t + 256] = (t + 256) * SLAB + atomicAdd(&bcur_pad[(t + 256) * 16],
                                                  cnt[t + 256]);
    // cnt[] is dead now — repurpose as lo[bucket] for the packed row index.
    {
        const unsigned long long Mll = M;
        cnt[t]       = (int)((((unsigned long long)t << 32) + Mll - 1) / Mll);
        cnt[t + 256] = (int)((((unsigned long long)(t + 256) << 32) + Mll - 1) / Mll);
    }
    __syncthreads();

#pragma unroll
    for (int k = 0; k < STG / 256; ++k) {
        if (rb[k] >= 0) {
            int lp = atomicAdd(&lcur[rb[k]], 1);
            sw[lp] = rs[k] | ((rd[k] - cnt[rb[k]]) << 17);
        }
    }
    __syncthreads();

    // emit per bucket: thread t owns buckets t and t+256; streams each run.
#pragma unroll
    for (int q = 0; q < 2; ++q) {
        int b  = t + q * 256;
        int s0 = loff[b];
        int cb = lcur[b] - s0;
        int g  = gbase[b];
        for (int j = 0; j < cb; ++j)
            pairs[g + j] = (unsigned)sw[s0 + j];
    }
}

// ------------------------- GEMM + attention logits body ---------------------
// RSTR : h row stride (ushorts).  EMBAL : embed fp32 al_s/al_d at row slots
// 32/34.  INBF : x rows are bf16 (stage-convert to fp32 in LDS).
template<int K, int OUTC, int H, int C, int NPT, int KCHUNK,
         int RSTR = OUTC, bool EMBAL = false, bool INBF = false>
__device__ __forceinline__ void gemm_al_body(char* smem, int vbid,
                                             const float* __restrict__ x,
                                             const float* __restrict__ W,
                                             const float* __restrict__ a_src,
                                             const float* __restrict__ a_dst,
                                             unsigned short* __restrict__ h,
                                             float* __restrict__ al_s,
                                             float* __restrict__ al_d,
                                             int n) {
    constexpr int COLG = OUTC / 4;
    constexpr int NG   = 256 / COLG;
    static_assert(NG * 8 == NPT, "tile mismatch");
    constexpr int LDX  = KCHUNK + 1;
    float* Xs = (float*)smem;                 // NPT*LDX
    float* Ws = Xs + NPT * LDX;               // KCHUNK*OUTC

    const int t    = threadIdx.x;
    const int mg   = t / COLG;
    const int cg   = t % COLG;
    const int base = vbid * NPT;

    v2f acc[8][2];
#pragma unroll
    for (int i = 0; i < 8; ++i) {
        acc[i][0] = (v2f){0.f, 0.f};
        acc[i][1] = (v2f){0.f, 0.f};
    }

    for (int kc = 0; kc < K; kc += KCHUNK) {
        __syncthreads();
        if constexpr (INBF) {
            const unsigned short* xb = (const unsigned short*)x;
            constexpr int G8  = KCHUNK / 8;       // 8-elem groups per node
            constexpr int TOT8 = NPT * G8;
#pragma unroll
            for (int r = 0; r < TOT8 / 256; ++r) {
                int g    = r * 256 + t;
                int node = g / G8;
                int kq   = g % G8;
                int gn   = base + node; if (gn > n - 1) gn = n - 1;
                const ushort4 v0 = *(const ushort4*)&xb[(size_t)gn * K + kc + kq * 8];
                const ushort4 v1 = *(const ushort4*)&xb[(size_t)gn * K + kc + kq * 8 + 4];
                float* d = &Xs[node * LDX + kq * 8];
                d[0] = bf2f(v0.x); d[1] = bf2f(v0.y);
                d[2] = bf2f(v0.z); d[3] = bf2f(v0.w);
                d[4] = bf2f(v1.x); d[5] = bf2f(v1.y);
                d[6] = bf2f(v1.z); d[7] = bf2f(v1.w);
            }
        } else {
            constexpr int F4R = KCHUNK / 4;
            constexpr int TOTF4 = NPT * F4R;
#pragma unroll
            for (int r = 0; r < TOTF4 / 256; ++r) {
                int f4   = r * 256 + t;
                int node = f4 / F4R;
                int kq   = f4 % F4R;
                int gn   = base + node; if (gn > n - 1) gn = n - 1;
                const float4 v = *(const float4*)&x[(size_t)gn * K + kc + kq * 4];
                float* d = &Xs[node * LDX + kq * 4];
                d[0] = v.x; d[1] = v.y; d[2] = v.z; d[3] = v.w;
            }
        }
        constexpr int WF4 = KCHUNK * OUTC / 4;
        for (int idx = t; idx < WF4; idx += 256)
            *(float4*)&Ws[idx * 4] = *(const float4*)&W[(size_t)kc * OUTC + idx * 4];
        __syncthreads();

#pragma unroll 4
        for (int k = 0; k < KCHUNK; ++k) {
            float4 b = *(const float4*)&Ws[k * OUTC + cg * 4];
            v2f b01 = {b.x, b.y};
            v2f b23 = {b.z, b.w};
#pragma unroll
            for (int i = 0; i < 8; ++i) {
                float av = Xs[(mg * 8 + i) * LDX + k];
                v2f a2 = {av, av};
                acc[i][0] = __builtin_elementwise_fma(a2, b01, acc[i][0]);
                acc[i][1] = __builtin_elementwise_fma(a2, b23, acc[i][1]);
            }
        }
    }

    const float4 as4 = *(const float4*)&a_src[cg * 4];
    const float4 ad4 = *(const float4*)&a_dst[cg * 4];
    constexpr int GPH = C / 4;
    const int head = cg / GPH;
#pragma unroll
    for (int i = 0; i < 8; ++i) {
        int gn = base + mg * 8 + i;
        bool ok = gn < n;
        float a0 = acc[i][0].x, a1 = acc[i][0].y;
        float a2 = acc[i][1].x, a3 = acc[i][1].y;
        if (ok) {
            ushort4 hv;
            hv.x = f2bf(a0); hv.y = f2bf(a1);
            hv.z = f2bf(a2); hv.w = f2bf(a3);
            *(ushort4*)&h[(size_t)gn * RSTR + cg * 4] = hv;
        }
        float ps = a0 * as4.x + a1 * as4.y + a2 * as4.z + a3 * as4.w;
        float pd = a0 * ad4.x + a1 * ad4.y + a2 * ad4.z + a3 * ad4.w;
#pragma unroll
        for (int s = 1; s < GPH; s <<= 1) {
            ps += __shfl_xor(ps, s, 64);
            pd += __shfl_xor(pd, s, 64);
        }
        if (ok && (cg % GPH) == 0) {
            if constexpr (EMBAL) {
                *(float*)&h[(size_t)gn * RSTR + 32] = ps;
                *(float*)&h[(size_t)gn * RSTR + 34] = pd;
            } else {
                al_s[(size_t)gn * H + head] = ps;
                al_d[(size_t)gn * H + head] = pd;
            }
        }
    }
}

// --------------------- CSR finalize body (smem-parameterized) ---------------
__device__ __forceinline__ void csr_body(char* smem, int b,
                                         const unsigned* __restrict__ pairs,
                                         const int* __restrict__ bcur_pad,
                                         unsigned M, int n,
                                         int* __restrict__ offsets,
                                         int* __restrict__ srcs) {
    int* bs  = (int*)smem;          // 512
    int* deg = bs + 512;            // 256
    int* sc  = deg + 256;           // 256
    int* cur = sc + 256;            // 256
    int* ebeg_p = cur + 256;        // 1

    const int t = threadIdx.x;
    const unsigned long long Mll = M;
    int lo = (int)((((unsigned long long)b << 32) + Mll - 1) / Mll);
    int hi = (int)((((unsigned long long)(b + 1) << 32) + Mll - 1) / Mll);
    if (lo > n) lo = n;
    if (hi > n) hi = n;
    const int R    = hi - lo;                 // <= ~196 < 256
    const int cntb = bcur_pad[b * 16];
    const unsigned* sp = pairs + (size_t)b * SLAB;

    bs[t] = bcur_pad[t * 16];
    bs[t + 256] = bcur_pad[(t + 256) * 16];
    __syncthreads();
    for (int off = 1; off < NBUCK; off <<= 1) {
        int v0 = (t >= off) ? bs[t - off] : 0;
        int v1 = (t + 256 >= off) ? bs[t + 256 - off] : 0;
        __syncthreads();
        bs[t] += v0; bs[t + 256] += v1;
        __syncthreads();
    }
    if (t == 0) *ebeg_p = (b == 0) ? 0 : bs[b - 1];
    if (b == NBUCK - 1 && t == 0) offsets[n] = bs[NBUCK - 1];
    __syncthreads();
    const int ebeg = *ebeg_p;

    deg[t] = 0;
    __syncthreads();
    for (int j = t; j < cntb; j += 256)
        atomicAdd(&deg[sp[j] >> 17], 1);
    __syncthreads();

    sc[t] = deg[t];
    __syncthreads();
    for (int off = 1; off < 256; off <<= 1) {
        int v = (t >= off) ? sc[t - off] : 0;
        __syncthreads();
        sc[t] += v;
        __syncthreads();
    }
    int e0 = sc[t] - deg[t];
    cur[t] = e0;
    if (t < R) offsets[lo + t] = ebeg + e0;
    __syncthreads();

    for (int j = t; j < cntb; j += 256) {
        unsigned w = sp[j];
        int pos = atomicAdd(&cur[w >> 17], 1);          // LDS atomic
        srcs[ebeg + pos] = (int)(w & 0x1FFFFu);
    }
}

// ------------- D1: scatter blocks + gemm1 blocks [0, GSPLIT) ---------------
__global__ __launch_bounds__(256)
void scatter_gemm_kernel(const int* __restrict__ ei, int e_real, int e_total,
                         unsigned M, int* __restrict__ bcur_pad,
                         unsigned* __restrict__ pairs, int ns,
                         const float* __restrict__ x,
                         const float* __restrict__ W1,
                         const float* __restrict__ as1,
                         const float* __restrict__ ad1,
                         unsigned short* __restrict__ h,
                         float* __restrict__ al_s,
                         float* __restrict__ al_d, int n) {
    __shared__ __align__(16) char smem[40960];  // max(gemm 25088, scatter 40960)
    if ((int)blockIdx.x < ns)
        scatter_body(smem, blockIdx.x, ei, e_real, e_total, M, bcur_pad, pairs);
    else
        gemm_al_body<128, 64, 8, 8, 128, 32>(smem, blockIdx.x - ns,
                                             x, W1, as1, ad1, h, al_s, al_d, n);
}

// ------------- D2: csr blocks (512) + gemm1 blocks [GSPLIT, 782) -----------
__global__ __launch_bounds__(256)
void csr_gemm_kernel(const unsigned* __restrict__ pairs,
                     const int* __restrict__ bcur_pad,
                     unsigned M,
                     int* __restrict__ offsets,
                     int* __restrict__ srcs,
                     const float* __restrict__ x,
                     const float* __restrict__ W1,
                     const float* __restrict__ as1,
                     const float* __restrict__ ad1,
                     unsigned short* __restrict__ h,
                     float* __restrict__ al_s,
                     float* __restrict__ al_d, int n) {
    __shared__ __align__(16) char smem[25088];  // max(gemm 25088, csr 5124)
    if ((int)blockIdx.x < NBUCK)
        csr_body(smem, blockIdx.x, pairs, bcur_pad, M, n, offsets, srcs);
    else
        gemm_al_body<128, 64, 8, 8, 128, 32>(smem,
                                             GSPLIT + ((int)blockIdx.x - NBUCK),
                                             x, W1, as1, ad1, h, al_s, al_d, n);
}

// D4: standalone layer-2 GEMM (bf16 inputs) -> 128B records
template<int K, int OUTC, int H, int C, int NPT, int KCHUNK, int RSTR,
         bool EMBAL, bool INBF>
__global__ __launch_bounds__(256)
void gemm_al_kernel(const float* __restrict__ x, const float* __restrict__ W,
                    const float* __restrict__ a_src, const float* __restrict__ a_dst,
                    unsigned short* __restrict__ h, float* __restrict__ al_s,
                    float* __restrict__ al_d, int n) {
    __shared__ __align__(16) char smem[(NPT * (KCHUNK + 1) + KCHUNK * OUTC) * 4];
    gemm_al_body<K, OUTC, H, C, NPT, KCHUNK, RSTR, EMBAL, INBF>(
        smem, blockIdx.x, x, W, a_src, a_dst, h, al_s, al_d, n);
}

// ------------------------- fused gather aggregation -------------------------
// wave = 1 dst node; lane = (edge_slot es, channel_group cg of 8 bf16).
// RSTR: hfeat row stride (ushorts). EMB: al embedded at slots 32/34.
// OBF : write output as packed bf16 (row stride OUTC ushorts).
template<int H, int C, int RSTR, bool EMB, bool OBF>
__global__ __launch_bounds__(256)
void gat_agg_kernel(const int* __restrict__ offsets,
                    const int* __restrict__ srcs,
                    const float* __restrict__ al_s,
                    const float* __restrict__ al_d,
                    const unsigned short* __restrict__ hfeat, // bf16 rows
                    const float* __restrict__ bias,
                    float* __restrict__ out, int n) {
    constexpr int OUTC = H * C;
    constexpr int CG   = OUTC / 8;           // channel groups (8 or 4)
    constexpr int ES   = 64 / CG;            // edge slots (8 or 16)
    const int wid  = (int)((blockIdx.x * blockDim.x + threadIdx.x) >> 6);
    const int lane = threadIdx.x & 63;
    const int cg   = lane % CG;
    const int es   = lane / CG;
    if (wid >= n) return;
    const int head = (cg * 8) / C;

    float aldv;
    if constexpr (EMB) aldv = *(const float*)&hfeat[(size_t)wid * RSTR + 34];
    else               aldv = al_d[(size_t)wid * H + head];
    const int beg = offsets[wid];
    const int end = offsets[wid + 1];
    const int deg = end - beg;

    v2f acc[4];
#pragma unroll
    for (int q = 0; q < 4; ++q) acc[q] = (v2f){0.f, 0.f};
    float dsum = 0.f;

#define LOADLS(sv) (EMB ? *(const float*)&hfeat[(size_t)(sv) * RSTR + 32] \
                        : al_s[(size_t)(sv) * H + head])

    if (deg <= ES) {
        int j = beg + es;
        bool v = j < end;
        int s = __builtin_nontemporal_load(&srcs[v ? j : beg]);
        const uint4 hv = *(const uint4*)&hfeat[(size_t)s * RSTR + cg * 8];
        float ls = LOADLS(s);
        float ex = v ? __expf(lrelu02(ls + aldv)) : 0.f;
        accum8(hv, ex, acc);
        dsum += ex;
    } else if (deg <= 2 * ES) {
        int sA = __builtin_nontemporal_load(&srcs[beg + es]);
        int jB = beg + ES + es;
        bool vB = jB < end;
        int sB = __builtin_nontemporal_load(&srcs[vB ? jB : beg]);
        const uint4 hvA = *(const uint4*)&hfeat[(size_t)sA * RSTR + cg * 8];
        const uint4 hvB = *(const uint4*)&hfeat[(size_t)sB * RSTR + cg * 8];
        float lsA = LOADLS(sA);
        float lsB = LOADLS(sB);
        float exA = __expf(lrelu02(lsA + aldv));
        float exB = vB ? __expf(lrelu02(lsB + aldv)) : 0.f;
        accum8(hvA, exA, acc);
        accum8(hvB, exB, acc);
        dsum += exA + exB;
    } else if (deg <= 4 * ES) {
        int sA = __builtin_nontemporal_load(&srcs[beg + es]);
        int sB = __builtin_nontemporal_load(&srcs[beg + ES + es]);
        int jC = beg + 2 * ES + es;
        int jD = beg + 3 * ES + es;
        bool vC = jC < end;
        bool vD = jD < end;
        int sC = __builtin_nontemporal_load(&srcs[vC ? jC : beg]);
        int sD = __builtin_nontemporal_load(&srcs[vD ? jD : beg]);
        const uint4 hvA = *(const uint4*)&hfeat[(size_t)sA * RSTR + cg * 8];
        const uint4 hvB = *(const uint4*)&hfeat[(size_t)sB * RSTR + cg * 8];
        const uint4 hvC = *(const uint4*)&hfeat[(size_t)sC * RSTR + cg * 8];
        const uint4 hvD = *(const uint4*)&hfeat[(size_t)sD * RSTR + cg * 8];
        float lsA = LOADLS(sA);
        float lsB = LOADLS(sB);
        float lsC = LOADLS(sC);
        float lsD = LOADLS(sD);
        float exA = __expf(lrelu02(lsA + aldv));
        float exB = __expf(lrelu02(lsB + aldv));
        float exC = vC ? __expf(lrelu02(lsC + aldv)) : 0.f;
        float exD = vD ? __expf(lrelu02(lsD + aldv)) : 0.f;
        accum8(hvA, exA, acc);
        accum8(hvB, exB, acc);
        accum8(hvC, exC, acc);
        accum8(hvD, exD, acc);
        dsum += (exA + exB) + (exC + exD);
    } else {
        for (int j0 = beg; j0 < end; j0 += 2 * ES) {
            int jA = j0 + es;
            int jB = j0 + ES + es;
            bool vA = jA < end;
            bool vB = jB < end;
            int sA = __builtin_nontemporal_load(&srcs[vA ? jA : beg]);
            int sB = __builtin_nontemporal_load(&srcs[vB ? jB : beg]);
            const uint4 hvA = *(const uint4*)&hfeat[(size_t)sA * RSTR + cg * 8];
            const uint4 hvB = *(const uint4*)&hfeat[(size_t)sB * RSTR + cg * 8];
            float lsA = LOADLS(sA);
            float lsB = LOADLS(sB);
            float exA = vA ? __expf(lrelu02(lsA + aldv)) : 0.f;
            float exB = vB ? __expf(lrelu02(lsB + aldv)) : 0.f;
            accum8(hvA, exA, acc);
            accum8(hvB, exB, acc);
            dsum += exA + exB;
        }
    }
#undef LOADLS

#pragma unroll
    for (int sh = CG; sh < 64; sh <<= 1) {
        dsum += __shfl_xor(dsum, sh, 64);
#pragma unroll
        for (int q = 0; q < 4; ++q) acc[q] += shfl_xor_v2(acc[q], sh);
    }

    if (es == 0) {
        float inv = 1.f / dsum;
        const float4 b0 = *(const float4*)&bias[cg * 8];
        const float4 b1v = *(const float4*)&bias[cg * 8 + 4];
        float o0 = acc[0].x * inv + b0.x;
        float o1 = acc[0].y * inv + b0.y;
        float o2 = acc[1].x * inv + b0.z;
        float o3 = acc[1].y * inv + b0.w;
        float o4 = acc[2].x * inv + b1v.x;
        float o5 = acc[2].y * inv + b1v.y;
        float o6 = acc[3].x * inv + b1v.z;
        float o7 = acc[3].y * inv + b1v.w;
        if constexpr (OBF) {
            unsigned p01 = (unsigned)f2bf(o0) | ((unsigned)f2bf(o1) << 16);
            unsigned p23 = (unsigned)f2bf(o2) | ((unsigned)f2bf(o3) << 16);
            unsigned p45 = (unsigned)f2bf(o4) | ((unsigned)f2bf(o5) << 16);
            unsigned p67 = (unsigned)f2bf(o6) | ((unsigned)f2bf(o7) << 16);
            uint4 pk; pk.x = p01; pk.y = p23; pk.z = p45; pk.w = p67;
            *(uint4*)&((unsigned short*)out)[(size_t)wid * OUTC + cg * 8] = pk;
        } else {
            float4 v0; v0.x = o0; v0.y = o1; v0.z = o2; v0.w = o3;
            float4 v1; v1.x = o4; v1.y = o5; v1.z = o6; v1.w = o7;
            *(float4*)&out[(size_t)wid * OUTC + cg * 8]     = v0;
            *(float4*)&out[(size_t)wid * OUTC + cg * 8 + 4] = v1;
        }
    }
}

// ---------------------------------------------------------------------------

extern "C" void kernel_launch(void* const* d_in, const int* in_sizes, int n_in,
                              void* d_out, int out_size, void* d_ws, size_t ws_size,
                              hipStream_t stream) {
    const float* x   = (const float*)d_in[0];
    const int*   ei  = (const int*)  d_in[1];
    const float* W1  = (const float*)d_in[2];
    const float* as1 = (const float*)d_in[3];
    const float* ad1 = (const float*)d_in[4];
    const float* b1  = (const float*)d_in[5];
    const float* W2  = (const float*)d_in[6];
    const float* as2 = (const float*)d_in[7];
    const float* ad2 = (const float*)d_in[8];
    const float* b2  = (const float*)d_in[9];
    float* out = (float*)d_out;

    const int n       = in_sizes[0] / 128;   // 100000
    const int e_real  = in_sizes[1] / 2;     // 1600000
    const int e_total = e_real + n;
    const unsigned M512 = (unsigned)(((unsigned long long)NBUCK << 32) / (unsigned)n);

    // ------------- workspace layout -------------
    unsigned short* h1u = (unsigned short*)d_ws;       // n*64 bf16 (layer-1 h;
                                                       //  reused as 128B recs)
    float* fws  = (float*)d_ws;
    float* als1 = fws  + (size_t)n * 32;               // n*8
    float* ald1 = als1 + (size_t)n * 8;                // n*8
    float* agg1 = ald1 + (size_t)n * 8;                // 25.6MB region:
    unsigned* pairs = (unsigned*)agg1;                 //   pairs (dead by D3)
    unsigned short* agg1b = (unsigned short*)agg1;     //   then bf16 agg1 n*64
    int* offsets  = (int*)(agg1 + (size_t)n * 64);     // n+1
    int* srcs     = offsets + (n + 1);                 // e_total
    int* bcur_pad = srcs + e_total;                    // NBUCK*16

    const int ns = (e_total + STG - 1) / STG;          // scatter blocks (208)
    const int g1 = (n + 127) / 128;                    // gemm1 blocks (782)

    // ------------- D1: scatter + gemm1[0,GSPLIT) -------------
    hipMemsetAsync(bcur_pad, 0, NBUCK * 16 * sizeof(int), stream);
    scatter_gemm_kernel<<<ns + GSPLIT, 256, 0, stream>>>(
        ei, e_real, e_total, M512, bcur_pad, pairs, ns,
        x, W1, as1, ad1, h1u, als1, ald1, n);

    // ------------- D2: csr finalize + gemm1[GSPLIT,g1) -------------
    csr_gemm_kernel<<<NBUCK + (g1 - GSPLIT), 256, 0, stream>>>(
        pairs, bcur_pad, M512, offsets, srcs,
        x, W1, as1, ad1, h1u, als1, ald1, n);

    // ------------- D3: layer 1 aggregation -> bf16 agg1 -------------
    gat_agg_kernel<8, 8, 64, false, true><<<(n + 3) / 4, 256, 0, stream>>>(
        offsets, srcs, als1, ald1, h1u, b1, (float*)agg1b, n);

    // ------------- D4: layer 2 GEMM (bf16 in) -> 128B records ------------
    gemm_al_kernel<64, 32, 1, 32, 256, 32, 64, true, true>
        <<<(n + 255) / 256, 256, 0, stream>>>(
        (const float*)agg1b, W2, as2, ad2, h1u, nullptr, nullptr, n);

    // ------------- D5: layer 2 aggregation (one line per edge) -----------
    gat_agg_kernel<1, 32, 64, true, false><<<(n + 3) / 4, 256, 0, stream>>>(
        offsets, srcs, nullptr, nullptr, h1u, b2, out, n);
}

// Round 11
// 255.052 us; speedup vs baseline: 1.0113x; 1.0027x over previous
//
#include <hip/hip_runtime.h>
#include <hip/hip_bf16.h>

// ---------------------------------------------------------------------------
// GAT (2 layers) — round 27: GSPLIT vertex probe 300 -> 450.
// R26 confirmed: bf16 agg1 halved D3 writes (dur 50->49.2, absmax
//   unchanged — bf16-h1 rounding dominates). Best 255.7us.
//   D3 floor: 147MB L2-fill / 49us = 3.0 TB/s random 128B line service,
//   rows exactly one fully-consumed line — nothing left to remove.
// R27: GSPLIT curve measured 0:266.6 / 300:256.7 / 782@40KB:263.3 — vertex
//   bracketed. At 450 both dispatches stay fully resident (D1 658 blk @
//   4/CU cap 1024; D2 844 blk @ 6/CU cap 1536); D1 absorbs +150 gemm
//   blocks in scatter idle cycles, D2 shortens. Single-variable probe.
// Structure:
//   D1  scatter_gemm : 512-bucket slab sort + gemm1 [0,450).
//   D2  csr_gemm     : per-bucket CSR finalize + gemm1 [450,782).
//   D3  gat_agg<8,8,OBF> : edge-slot gather -> bf16 agg1 (floor ~49us).
//   D4  gemm_al<INBF> (layer 2) -> 128B records (h2 + embedded al2).
//   D5  gat_agg<1,32,EMB> : one-line-per-edge gather -> out.
// Rejected by experiment: agg+gemm2 fusion (R12/R13/R21), STG=2048 (R17),
// GSPLIT=0 (R23), pipeline repack (R15), nt-loads (R6), packed-math in agg
// (R10), D5 record-embedding gain (R24 neutral), packed gemm fp32 (R25
// neutral — latency-hidden).
// ---------------------------------------------------------------------------

#define SLAB  4096      // global per-bucket slab capacity (packed words)
#define STG   8192      // per-block staging slab (edges)
#define NBUCK 512
#define GSPLIT 450      // gemm1 blocks packed into D1

typedef float v2f __attribute__((ext_vector_type(2)));

__device__ __forceinline__ float lrelu02(float x) { return x > 0.f ? x : 0.2f * x; }

__device__ __forceinline__ unsigned short f2bf(float v) {
    __hip_bfloat16 b = __float2bfloat16(v);
    return __builtin_bit_cast(unsigned short, b);
}

__device__ __forceinline__ float bf2f(unsigned short u) {
    return __uint_as_float(((unsigned)u) << 16);
}

__device__ __forceinline__ void accum8(uint4 hv, float ex, v2f* acc) {
    v2f ex2 = {ex, ex};
#pragma unroll
    for (int q = 0; q < 4; ++q) {
        unsigned u = (&hv.x)[q];
        v2f h2 = {__uint_as_float(u << 16), __uint_as_float(u & 0xffff0000u)};
        acc[q] = __builtin_elementwise_fma(h2, ex2, acc[q]);
    }
}

__device__ __forceinline__ v2f shfl_xor_v2(v2f v, int mask) {
    v2f r;
    r.x = __shfl_xor(v.x, mask, 64);
    r.y = __shfl_xor(v.y, mask, 64);
    return r;
}

// ----------------------- scatter body (512-bucket slab sort) ----------------
__device__ __forceinline__ void scatter_body(char* smem, int vbid,
                                             const int* __restrict__ ei,
                                             int e_real, int e_total, unsigned M,
                                             int* __restrict__ bcur_pad,
                                             unsigned* __restrict__ pairs) {
    int* cnt   = (int*)smem;                     // 512 (reused as lo[] later)
    int* loff  = cnt + 512;                      // 512
    int* lcur  = loff + 512;                     // 512
    int* gbase = lcur + 512;                     // 512
    int* sw    = gbase + 512;                    // STG packed words

    const int t = threadIdx.x;
    const int base = vbid * STG;
    cnt[t] = 0; cnt[t + 256] = 0;
    __syncthreads();

    int rs[STG / 256], rd[STG / 256], rb[STG / 256];
#pragma unroll
    for (int k = 0; k < STG / 256; ++k) {
        int i = base + k * 256 + t;
        bool val = i < e_total;
        int s = 0, d = 0;
        if (val) {
            if (i < e_real) { s = ei[i]; d = ei[e_real + i]; }
            else            { s = d = i - e_real; }
        }
        int b = val ? (int)__umulhi((unsigned)d, M) : -1;
        rs[k] = s; rd[k] = d; rb[k] = b;
        if (val) atomicAdd(&cnt[b], 1);
    }
    __syncthreads();

    loff[t] = cnt[t]; loff[t + 256] = cnt[t + 256];
    __syncthreads();
    for (int off = 1; off < 512; off <<= 1) {
        int v0 = (t >= off) ? loff[t - off] : 0;
        int v1 = (t + 256 >= off) ? loff[t + 256 - off] : 0;
        __syncthreads();
        loff[t] += v0; loff[t + 256] += v1;
        __syncthreads();
    }
    int e0 = loff[t] - cnt[t];
    int e1 = loff[t + 256] - cnt[t + 256];
    loff[t] = e0;           loff[t + 256] = e1;
    lcur[t] = e0;           lcur[t + 256] = e1;
    gbase[t]       = t * SLAB         + atomicAdd(&bcur_pad[t * 16], cnt[t]);
    gbase[t + 256] = (t + 256) * SLAB + atomicAdd(&bcur_pad[(t + 256) * 16],
                                                  cnt[t + 256]);
    // cnt[] is dead now — repurpose as lo[bucket] for the packed row index.
    {
        const unsigned long long Mll = M;
        cnt[t]       = (int)((((unsigned long long)t << 32) + Mll - 1) / Mll);
        cnt[t + 256] = (int)((((unsigned long long)(t + 256) << 32) + Mll - 1) / Mll);
    }
    __syncthreads();

#pragma unroll
    for (int k = 0; k < STG / 256; ++k) {
        if (rb[k] >= 0) {
            int lp = atomicAdd(&lcur[rb[k]], 1);
            sw[lp] = rs[k] | ((rd[k] - cnt[rb[k]]) << 17);
        }
    }
    __syncthreads();

    // emit per bucket: thread t owns buckets t and t+256; streams each run.
#pragma unroll
    for (int q = 0; q < 2; ++q) {
        int b  = t + q * 256;
        int s0 = loff[b];
        int cb = lcur[b] - s0;
        int g  = gbase[b];
        for (int j = 0; j < cb; ++j)
            pairs[g + j] = (unsigned)sw[s0 + j];
    }
}

// ------------------------- GEMM + attention logits body ---------------------
// RSTR : h row stride (ushorts).  EMBAL : embed fp32 al_s/al_d at row slots
// 32/34.  INBF : x rows are bf16 (stage-convert to fp32 in LDS).
template<int K, int OUTC, int H, int C, int NPT, int KCHUNK,
         int RSTR = OUTC, bool EMBAL = false, bool INBF = false>
__device__ __forceinline__ void gemm_al_body(char* smem, int vbid,
                                             const float* __restrict__ x,
                                             const float* __restrict__ W,
                                             const float* __restrict__ a_src,
                                             const float* __restrict__ a_dst,
                                             unsigned short* __restrict__ h,
                                             float* __restrict__ al_s,
                                             float* __restrict__ al_d,
                                             int n) {
    constexpr int COLG = OUTC / 4;
    constexpr int NG   = 256 / COLG;
    static_assert(NG * 8 == NPT, "tile mismatch");
    constexpr int LDX  = KCHUNK + 1;
    float* Xs = (float*)smem;                 // NPT*LDX
    float* Ws = Xs + NPT * LDX;               // KCHUNK*OUTC

    const int t    = threadIdx.x;
    const int mg   = t / COLG;
    const int cg   = t % COLG;
    const int base = vbid * NPT;

    v2f acc[8][2];
#pragma unroll
    for (int i = 0; i < 8; ++i) {
        acc[i][0] = (v2f){0.f, 0.f};
        acc[i][1] = (v2f){0.f, 0.f};
    }

    for (int kc = 0; kc < K; kc += KCHUNK) {
        __syncthreads();
        if constexpr (INBF) {
            const unsigned short* xb = (const unsigned short*)x;
            constexpr int G8  = KCHUNK / 8;       // 8-elem groups per node
            constexpr int TOT8 = NPT * G8;
#pragma unroll
            for (int r = 0; r < TOT8 / 256; ++r) {
                int g    = r * 256 + t;
                int node = g / G8;
                int kq   = g % G8;
                int gn   = base + node; if (gn > n - 1) gn = n - 1;
                const ushort4 v0 = *(const ushort4*)&xb[(size_t)gn * K + kc + kq * 8];
                const ushort4 v1 = *(const ushort4*)&xb[(size_t)gn * K + kc + kq * 8 + 4];
                float* d = &Xs[node * LDX + kq * 8];
                d[0] = bf2f(v0.x); d[1] = bf2f(v0.y);
                d[2] = bf2f(v0.z); d[3] = bf2f(v0.w);
                d[4] = bf2f(v1.x); d[5] = bf2f(v1.y);
                d[6] = bf2f(v1.z); d[7] = bf2f(v1.w);
            }
        } else {
            constexpr int F4R = KCHUNK / 4;
            constexpr int TOTF4 = NPT * F4R;
#pragma unroll
            for (int r = 0; r < TOTF4 / 256; ++r) {
                int f4   = r * 256 + t;
                int node = f4 / F4R;
                int kq   = f4 % F4R;
                int gn   = base + node; if (gn > n - 1) gn = n - 1;
                const float4 v = *(const float4*)&x[(size_t)gn * K + kc + kq * 4];
                float* d = &Xs[node * LDX + kq * 4];
                d[0] = v.x; d[1] = v.y; d[2] = v.z; d[3] = v.w;
            }
        }
        constexpr int WF4 = KCHUNK * OUTC / 4;
        for (int idx = t; idx < WF4; idx += 256)
            *(float4*)&Ws[idx * 4] = *(const float4*)&W[(size_t)kc * OUTC + idx * 4];
        __syncthreads();

#pragma unroll 4
        for (int k = 0; k < KCHUNK; ++k) {
            float4 b = *(const float4*)&Ws[k * OUTC + cg * 4];
            v2f b01 = {b.x, b.y};
            v2f b23 = {b.z, b.w};
#pragma unroll
            for (int i = 0; i < 8; ++i) {
                float av = Xs[(mg * 8 + i) * LDX + k];
                v2f a2 = {av, av};
                acc[i][0] = __builtin_elementwise_fma(a2, b01, acc[i][0]);
                acc[i][1] = __builtin_elementwise_fma(a2, b23, acc[i][1]);
            }
        }
    }

    const float4 as4 = *(const float4*)&a_src[cg * 4];
    const float4 ad4 = *(const float4*)&a_dst[cg * 4];
    constexpr int GPH = C / 4;
    const int head = cg / GPH;
#pragma unroll
    for (int i = 0; i < 8; ++i) {
        int gn = base + mg * 8 + i;
        bool ok = gn < n;
        float a0 = acc[i][0].x, a1 = acc[i][0].y;
        float a2 = acc[i][1].x, a3 = acc[i][1].y;
        if (ok) {
            ushort4 hv;
            hv.x = f2bf(a0); hv.y = f2bf(a1);
            hv.z = f2bf(a2); hv.w = f2bf(a3);
            *(ushort4*)&h[(size_t)gn * RSTR + cg * 4] = hv;
        }
        float ps = a0 * as4.x + a1 * as4.y + a2 * as4.z + a3 * as4.w;
        float pd = a0 * ad4.x + a1 * ad4.y + a2 * ad4.z + a3 * ad4.w;
#pragma unroll
        for (int s = 1; s < GPH; s <<= 1) {
            ps += __shfl_xor(ps, s, 64);
            pd += __shfl_xor(pd, s, 64);
        }
        if (ok && (cg % GPH) == 0) {
            if constexpr (EMBAL) {
                *(float*)&h[(size_t)gn * RSTR + 32] = ps;
                *(float*)&h[(size_t)gn * RSTR + 34] = pd;
            } else {
                al_s[(size_t)gn * H + head] = ps;
                al_d[(size_t)gn * H + head] = pd;
            }
        }
    }
}

// --------------------- CSR finalize body (smem-parameterized) ---------------
__device__ __forceinline__ void csr_body(char* smem, int b,
                                         const unsigned* __restrict__ pairs,
                                         const int* __restrict__ bcur_pad,
                                         unsigned M, int n,
                                         int* __restrict__ offsets,
                                         int* __restrict__ srcs) {
    int* bs  = (int*)smem;          // 512
    int* deg = bs + 512;            // 256
    int* sc  = deg + 256;           // 256
    int* cur = sc + 256;            // 256
    int* ebeg_p = cur + 256;        // 1

    const int t = threadIdx.x;
    const unsigned long long Mll = M;
    int lo = (int)((((unsigned long long)b << 32) + Mll - 1) / Mll);
    int hi = (int)((((unsigned long long)(b + 1) << 32) + Mll - 1) / Mll);
    if (lo > n) lo = n;
    if (hi > n) hi = n;
    const int R    = hi - lo;                 // <= ~196 < 256
    const int cntb = bcur_pad[b * 16];
    const unsigned* sp = pairs + (size_t)b * SLAB;

    bs[t] = bcur_pad[t * 16];
    bs[t + 256] = bcur_pad[(t + 256) * 16];
    __syncthreads();
    for (int off = 1; off < NBUCK; off <<= 1) {
        int v0 = (t >= off) ? bs[t - off] : 0;
        int v1 = (t + 256 >= off) ? bs[t + 256 - off] : 0;
        __syncthreads();
        bs[t] += v0; bs[t + 256] += v1;
        __syncthreads();
    }
    if (t == 0) *ebeg_p = (b == 0) ? 0 : bs[b - 1];
    if (b == NBUCK - 1 && t == 0) offsets[n] = bs[NBUCK - 1];
    __syncthreads();
    const int ebeg = *ebeg_p;

    deg[t] = 0;
    __syncthreads();
    for (int j = t; j < cntb; j += 256)
        atomicAdd(&deg[sp[j] >> 17], 1);
    __syncthreads();

    sc[t] = deg[t];
    __syncthreads();
    for (int off = 1; off < 256; off <<= 1) {
        int v = (t >= off) ? sc[t - off] : 0;
        __syncthreads();
        sc[t] += v;
        __syncthreads();
    }
    int e0 = sc[t] - deg[t];
    cur[t] = e0;
    if (t < R) offsets[lo + t] = ebeg + e0;
    __syncthreads();

    for (int j = t; j < cntb; j += 256) {
        unsigned w = sp[j];
        int pos = atomicAdd(&cur[w >> 17], 1);          // LDS atomic
        srcs[ebeg + pos] = (int)(w & 0x1FFFFu);
    }
}

// ------------- D1: scatter blocks + gemm1 blocks [0, GSPLIT) ---------------
__global__ __launch_bounds__(256)
void scatter_gemm_kernel(const int* __restrict__ ei, int e_real, int e_total,
                         unsigned M, int* __restrict__ bcur_pad,
                         unsigned* __restrict__ pairs, int ns,
                         const float* __restrict__ x,
                         const float* __restrict__ W1,
                         const float* __restrict__ as1,
                         const float* __restrict__ ad1,
                         unsigned short* __restrict__ h,
                         float* __restrict__ al_s,
                         float* __restrict__ al_d, int n) {
    __shared__ __align__(16) char smem[40960];  // max(gemm 25088, scatter 40960)
    if ((int)blockIdx.x < ns)
        scatter_body(smem, blockIdx.x, ei, e_real, e_total, M, bcur_pad, pairs);
    else
        gemm_al_body<128, 64, 8, 8, 128, 32>(smem, blockIdx.x - ns,
                                             x, W1, as1, ad1, h, al_s, al_d, n);
}

// ------------- D2: csr blocks (512) + gemm1 blocks [GSPLIT, 782) -----------
__global__ __launch_bounds__(256)
void csr_gemm_kernel(const unsigned* __restrict__ pairs,
                     const int* __restrict__ bcur_pad,
                     unsigned M,
                     int* __restrict__ offsets,
                     int* __restrict__ srcs,
                     const float* __restrict__ x,
                     const float* __restrict__ W1,
                     const float* __restrict__ as1,
                     const float* __restrict__ ad1,
                     unsigned short* __restrict__ h,
                     float* __restrict__ al_s,
                     float* __restrict__ al_d, int n) {
    __shared__ __align__(16) char smem[25088];  // max(gemm 25088, csr 5124)
    if ((int)blockIdx.x < NBUCK)
        csr_body(smem, blockIdx.x, pairs, bcur_pad, M, n, offsets, srcs);
    else
        gemm_al_body<128, 64, 8, 8, 128, 32>(smem,
                                             GSPLIT + ((int)blockIdx.x - NBUCK),
                                             x, W1, as1, ad1, h, al_s, al_d, n);
}

// D4: standalone layer-2 GEMM (bf16 inputs) -> 128B records
template<int K, int OUTC, int H, int C, int NPT, int KCHUNK, int RSTR,
         bool EMBAL, bool INBF>
__global__ __launch_bounds__(256)
void gemm_al_kernel(const float* __restrict__ x, const float* __restrict__ W,
                    const float* __restrict__ a_src, const float* __restrict__ a_dst,
                    unsigned short* __restrict__ h, float* __restrict__ al_s,
                    float* __restrict__ al_d, int n) {
    __shared__ __align__(16) char smem[(NPT * (KCHUNK + 1) + KCHUNK * OUTC) * 4];
    gemm_al_body<K, OUTC, H, C, NPT, KCHUNK, RSTR, EMBAL, INBF>(
        smem, blockIdx.x, x, W, a_src, a_dst, h, al_s, al_d, n);
}

// ------------------------- fused gather aggregation -------------------------
// wave = 1 dst node; lane = (edge_slot es, channel_group cg of 8 bf16).
// RSTR: hfeat row stride (ushorts). EMB: al embedded at slots 32/34.
// OBF : write output as packed bf16 (row stride OUTC ushorts).
template<int H, int C, int RSTR, bool EMB, bool OBF>
__global__ __launch_bounds__(256)
void gat_agg_kernel(const int* __restrict__ offsets,
                    const int* __restrict__ srcs,
                    const float* __restrict__ al_s,
                    const float* __restrict__ al_d,
                    const unsigned short* __restrict__ hfeat, // bf16 rows
                    const float* __restrict__ bias,
                    float* __restrict__ out, int n) {
    constexpr int OUTC = H * C;
    constexpr int CG   = OUTC / 8;           // channel groups (8 or 4)
    constexpr int ES   = 64 / CG;            // edge slots (8 or 16)
    const int wid  = (int)((blockIdx.x * blockDim.x + threadIdx.x) >> 6);
    const int lane = threadIdx.x & 63;
    const int cg   = lane % CG;
    const int es   = lane / CG;
    if (wid >= n) return;
    const int head = (cg * 8) / C;

    float aldv;
    if constexpr (EMB) aldv = *(const float*)&hfeat[(size_t)wid * RSTR + 34];
    else               aldv = al_d[(size_t)wid * H + head];
    const int beg = offsets[wid];
    const int end = offsets[wid + 1];
    const int deg = end - beg;

    v2f acc[4];
#pragma unroll
    for (int q = 0; q < 4; ++q) acc[q] = (v2f){0.f, 0.f};
    float dsum = 0.f;

#define LOADLS(sv) (EMB ? *(const float*)&hfeat[(size_t)(sv) * RSTR + 32] \
                        : al_s[(size_t)(sv) * H + head])

    if (deg <= ES) {
        int j = beg + es;
        bool v = j < end;
        int s = __builtin_nontemporal_load(&srcs[v ? j : beg]);
        const uint4 hv = *(const uint4*)&hfeat[(size_t)s * RSTR + cg * 8];
        float ls = LOADLS(s);
        float ex = v ? __expf(lrelu02(ls + aldv)) : 0.f;
        accum8(hv, ex, acc);
        dsum += ex;
    } else if (deg <= 2 * ES) {
        int sA = __builtin_nontemporal_load(&srcs[beg + es]);
        int jB = beg + ES + es;
        bool vB = jB < end;
        int sB = __builtin_nontemporal_load(&srcs[vB ? jB : beg]);
        const uint4 hvA = *(const uint4*)&hfeat[(size_t)sA * RSTR + cg * 8];
        const uint4 hvB = *(const uint4*)&hfeat[(size_t)sB * RSTR + cg * 8];
        float lsA = LOADLS(sA);
        float lsB = LOADLS(sB);
        float exA = __expf(lrelu02(lsA + aldv));
        float exB = vB ? __expf(lrelu02(lsB + aldv)) : 0.f;
        accum8(hvA, exA, acc);
        accum8(hvB, exB, acc);
        dsum += exA + exB;
    } else if (deg <= 4 * ES) {
        int sA = __builtin_nontemporal_load(&srcs[beg + es]);
        int sB = __builtin_nontemporal_load(&srcs[beg + ES + es]);
        int jC = beg + 2 * ES + es;
        int jD = beg + 3 * ES + es;
        bool vC = jC < end;
        bool vD = jD < end;
        int sC = __builtin_nontemporal_load(&srcs[vC ? jC : beg]);
        int sD = __builtin_nontemporal_load(&srcs[vD ? jD : beg]);
        const uint4 hvA = *(const uint4*)&hfeat[(size_t)sA * RSTR + cg * 8];
        const uint4 hvB = *(const uint4*)&hfeat[(size_t)sB * RSTR + cg * 8];
        const uint4 hvC = *(const uint4*)&hfeat[(size_t)sC * RSTR + cg * 8];
        const uint4 hvD = *(const uint4*)&hfeat[(size_t)sD * RSTR + cg * 8];
        float lsA = LOADLS(sA);
        float lsB = LOADLS(sB);
        float lsC = LOADLS(sC);
        float lsD = LOADLS(sD);
        float exA = __expf(lrelu02(lsA + aldv));
        float exB = __expf(lrelu02(lsB + aldv));
        float exC = vC ? __expf(lrelu02(lsC + aldv)) : 0.f;
        float exD = vD ? __expf(lrelu02(lsD + aldv)) : 0.f;
        accum8(hvA, exA, acc);
        accum8(hvB, exB, acc);
        accum8(hvC, exC, acc);
        accum8(hvD, exD, acc);
        dsum += (exA + exB) + (exC + exD);
    } else {
        for (int j0 = beg; j0 < end; j0 += 2 * ES) {
            int jA = j0 + es;
            int jB = j0 + ES + es;
            bool vA = jA < end;
            bool vB = jB < end;
            int sA = __builtin_nontemporal_load(&srcs[vA ? jA : beg]);
            int sB = __builtin_nontemporal_load(&srcs[vB ? jB : beg]);
            const uint4 hvA = *(const uint4*)&hfeat[(size_t)sA * RSTR + cg * 8];
            const uint4 hvB = *(const uint4*)&hfeat[(size_t)sB * RSTR + cg * 8];
            float lsA = LOADLS(sA);
            float lsB = LOADLS(sB);
            float exA = vA ? __expf(lrelu02(lsA + aldv)) : 0.f;
            float exB = vB ? __expf(lrelu02(lsB + aldv)) : 0.f;
            accum8(hvA, exA, acc);
            accum8(hvB, exB, acc);
            dsum += exA + exB;
        }
    }
#undef LOADLS

#pragma unroll
    for (int sh = CG; sh < 64; sh <<= 1) {
        dsum += __shfl_xor(dsum, sh, 64);
#pragma unroll
        for (int q = 0; q < 4; ++q) acc[q] += shfl_xor_v2(acc[q], sh);
    }

    if (es == 0) {
        float inv = 1.f / dsum;
        const float4 b0 = *(const float4*)&bias[cg * 8];
        const float4 b1v = *(const float4*)&bias[cg * 8 + 4];
        float o0 = acc[0].x * inv + b0.x;
        float o1 = acc[0].y * inv + b0.y;
        float o2 = acc[1].x * inv + b0.z;
        float o3 = acc[1].y * inv + b0.w;
        float o4 = acc[2].x * inv + b1v.x;
        float o5 = acc[2].y * inv + b1v.y;
        float o6 = acc[3].x * inv + b1v.z;
        float o7 = acc[3].y * inv + b1v.w;
        if constexpr (OBF) {
            unsigned p01 = (unsigned)f2bf(o0) | ((unsigned)f2bf(o1) << 16);
            unsigned p23 = (unsigned)f2bf(o2) | ((unsigned)f2bf(o3) << 16);
            unsigned p45 = (unsigned)f2bf(o4) | ((unsigned)f2bf(o5) << 16);
            unsigned p67 = (unsigned)f2bf(o6) | ((unsigned)f2bf(o7) << 16);
            uint4 pk; pk.x = p01; pk.y = p23; pk.z = p45; pk.w = p67;
            *(uint4*)&((unsigned short*)out)[(size_t)wid * OUTC + cg * 8] = pk;
        } else {
            float4 v0; v0.x = o0; v0.y = o1; v0.z = o2; v0.w = o3;
            float4 v1; v1.x = o4; v1.y = o5; v1.z = o6; v1.w = o7;
            *(float4*)&out[(size_t)wid * OUTC + cg * 8]     = v0;
            *(float4*)&out[(size_t)wid * OUTC + cg * 8 + 4] = v1;
        }
    }
}

// ---------------------------------------------------------------------------

extern "C" void kernel_launch(void* const* d_in, const int* in_sizes, int n_in,
                              void* d_out, int out_size, void* d_ws, size_t ws_size,
                              hipStream_t stream) {
    const float* x   = (const float*)d_in[0];
    const int*   ei  = (const int*)  d_in[1];
    const float* W1  = (const float*)d_in[2];
    const float* as1 = (const float*)d_in[3];
    const float* ad1 = (const float*)d_in[4];
    const float* b1  = (const float*)d_in[5];
    const float* W2  = (const float*)d_in[6];
    const float* as2 = (const float*)d_in[7];
    const float* ad2 = (const float*)d_in[8];
    const float* b2  = (const float*)d_in[9];
    float* out = (float*)d_out;

    const int n       = in_sizes[0] / 128;   // 100000
    const int e_real  = in_sizes[1] / 2;     // 1600000
    const int e_total = e_real + n;
    const unsigned M512 = (unsigned)(((unsigned long long)NBUCK << 32) / (unsigned)n);

    // ------------- workspace layout -------------
    unsigned short* h1u = (unsigned short*)d_ws;       // n*64 bf16 (layer-1 h;
                                                       //  reused as 128B recs)
    float* fws  = (float*)d_ws;
    float* als1 = fws  + (size_t)n * 32;               // n*8
    float* ald1 = als1 + (size_t)n * 8;                // n*8
    float* agg1 = ald1 + (size_t)n * 8;                // 25.6MB region:
    unsigned* pairs = (unsigned*)agg1;                 //   pairs (dead by D3)
    unsigned short* agg1b = (unsigned short*)agg1;     //   then bf16 agg1 n*64
    int* offsets  = (int*)(agg1 + (size_t)n * 64);     // n+1
    int* srcs     = offsets + (n + 1);                 // e_total
    int* bcur_pad = srcs + e_total;                    // NBUCK*16

    const int ns = (e_total + STG - 1) / STG;          // scatter blocks (208)
    const int g1 = (n + 127) / 128;                    // gemm1 blocks (782)

    // ------------- D1: scatter + gemm1[0,GSPLIT) -------------
    hipMemsetAsync(bcur_pad, 0, NBUCK * 16 * sizeof(int), stream);
    scatter_gemm_kernel<<<ns + GSPLIT, 256, 0, stream>>>(
        ei, e_real, e_total, M512, bcur_pad, pairs, ns,
        x, W1, as1, ad1, h1u, als1, ald1, n);

    // ------------- D2: csr finalize + gemm1[GSPLIT,g1) -------------
    csr_gemm_kernel<<<NBUCK + (g1 - GSPLIT), 256, 0, stream>>>(
        pairs, bcur_pad, M512, offsets, srcs,
        x, W1, as1, ad1, h1u, als1, ald1, n);

    // ------------- D3: layer 1 aggregation -> bf16 agg1 -------------
    gat_agg_kernel<8, 8, 64, false, true><<<(n + 3) / 4, 256, 0, stream>>>(
        offsets, srcs, als1, ald1, h1u, b1, (float*)agg1b, n);

    // ------------- D4: layer 2 GEMM (bf16 in) -> 128B records ------------
    gemm_al_kernel<64, 32, 1, 32, 256, 32, 64, true, true>
        <<<(n + 255) / 256, 256, 0, stream>>>(
        (const float*)agg1b, W2, as2, ad2, h1u, nullptr, nullptr, n);

    // ------------- D5: layer 2 aggregation (one line per edge) -----------
    gat_agg_kernel<1, 32, 64, true, false><<<(n + 3) / 4, 256, 0, stream>>>(
        offsets, srcs, nullptr, nullptr, h1u, b2, out, n);
}